// Round 1
// baseline (332.993 us; speedup 1.0000x reference)
//
#include <hip/hip_runtime.h>
#include <math.h>

#define LN 4096
#define CN 64
#define BQ 32
#define NTH 256

// ws offsets (in floats)
#define OFF_CHAN_SUM   0        // 2048
#define OFF_CHAN_JERK  2048     // 2048
#define OFF_CHAN_JRATE 4096     // 2048
#define OFF_CHAN_ZCR   6144     // 2048
#define OFF_SVM        8192     // 32*8
#define OFF_SPEC       8448     // 32*3
#define OFF_EFF_B      8544     // 2048
#define OFF_GN         10592    // 32*2 doubles = 128 floats (8B aligned: 10592*4 % 8 == 0)
#define OFF_EFF_W      10720    // 2048*64
// total = 141792 floats = 567168 bytes

// ---------------- K0: zero the atomic accumulators ----------------
__global__ void k0_zero(float* __restrict__ ws) {
  int t = threadIdx.x;
  if (t < 96)  ws[OFF_SPEC + t] = 0.f;
  if (t < 128) ws[OFF_GN + t] = 0.f;
}

// ---------------- K1: per-(b,c) scans ----------------
__global__ __launch_bounds__(NTH) void k1_chan(const float* __restrict__ x, float* __restrict__ ws) {
  int bc = blockIdx.x;
  const float* row = x + (size_t)bc * LN;
  __shared__ float sx[LN];
  __shared__ double rs[NTH];
  __shared__ float rf[NTH];
  __shared__ int ri[NTH];
  for (int l = threadIdx.x; l < LN; l += NTH) sx[l] = row[l];
  __syncthreads();
  double lsum = 0.0; float jm = 0.f, jrm = 0.f; int zc = 0;
  for (int l = threadIdx.x; l < LN; l += NTH) {
    float a = sx[l];
    lsum += a;
    if (l < LN - 1) {
      float b2 = sx[l + 1];
      jm = fmaxf(jm, fabsf(b2 - a));
      if (a * b2 < 0.f) zc++;
      if (l < LN - 2) {
        float c2 = sx[l + 2];
        jrm = fmaxf(jrm, fabsf(c2 - 2.f * b2 + a));
      }
    }
  }
  rs[threadIdx.x] = lsum; rf[threadIdx.x] = jm; ri[threadIdx.x] = zc;
  __syncthreads();
  for (int s = NTH / 2; s > 0; s >>= 1) {
    if (threadIdx.x < s) {
      rs[threadIdx.x] += rs[threadIdx.x + s];
      rf[threadIdx.x] = fmaxf(rf[threadIdx.x], rf[threadIdx.x + s]);
      ri[threadIdx.x] += ri[threadIdx.x + s];
    }
    __syncthreads();
  }
  double sum_all = rs[0]; float jm_all = rf[0]; int zc_all = ri[0];
  __syncthreads();
  rf[threadIdx.x] = jrm; __syncthreads();
  for (int s = NTH / 2; s > 0; s >>= 1) {
    if (threadIdx.x < s) rf[threadIdx.x] = fmaxf(rf[threadIdx.x], rf[threadIdx.x + s]);
    __syncthreads();
  }
  if (threadIdx.x == 0) {
    ws[OFF_CHAN_SUM + bc]   = (float)sum_all;
    ws[OFF_CHAN_JERK + bc]  = jm_all * 50.f;
    ws[OFF_CHAN_JRATE + bc] = rf[0] * 2500.f;
    ws[OFF_CHAN_ZCR + bc]   = (float)zc_all;
  }
}

// ---------------- K2: svm stats per b ----------------
__global__ __launch_bounds__(NTH) void k2_svm(const float* __restrict__ x, float* __restrict__ ws) {
  int b = blockIdx.x;
  __shared__ float svm[LN];
  __shared__ double red[NTH];
  __shared__ float redf[NTH];
  __shared__ float bcast[2];
  const float* xb = x + (size_t)b * CN * LN;
  for (int l = threadIdx.x; l < LN; l += NTH) {
    float acc = 0.f;
#pragma unroll
    for (int c = 0; c < CN; c++) { float v = xb[(size_t)c * LN + l]; acc = fmaf(v, v, acc); }
    svm[l] = sqrtf(acc);
  }
  __syncthreads();
  const int third = LN / 3;  // 1365
  double s = 0, s2 = 0, s2h = 0, s2h2 = 0, spre = 0, spost = 0;
  float mx = -1e30f, mxmid = -1e30f;
  for (int l = threadIdx.x; l < LN; l += NTH) {
    float v = svm[l];
    s += v; s2 += (double)v * (double)v;
    mx = fmaxf(mx, v);
    if (l >= LN / 2) { s2h += v; s2h2 += (double)v * (double)v; }
    if (l < third) spre += v;
    else if (l < 2 * third) mxmid = fmaxf(mxmid, v);
    else spost += v;
  }
  double vals[6] = { s, s2, s2h, s2h2, spre, spost };
  double out6[6];
  for (int q = 0; q < 6; q++) {
    red[threadIdx.x] = vals[q]; __syncthreads();
    for (int st = NTH / 2; st > 0; st >>= 1) {
      if (threadIdx.x < st) red[threadIdx.x] += red[threadIdx.x + st];
      __syncthreads();
    }
    out6[q] = red[0]; __syncthreads();
  }
  float fvals[2] = { mx, mxmid }; float outf[2];
  for (int q = 0; q < 2; q++) {
    redf[threadIdx.x] = fvals[q]; __syncthreads();
    for (int st = NTH / 2; st > 0; st >>= 1) {
      if (threadIdx.x < st) redf[threadIdx.x] = fmaxf(redf[threadIdx.x], redf[threadIdx.x + st]);
      __syncthreads();
    }
    outf[q] = redf[0]; __syncthreads();
  }
  if (threadIdx.x == 0) {
    double mean = out6[0] / LN;
    double var = (out6[1] - out6[0] * out6[0] / LN) / (LN - 1);
    if (var < 0) var = 0;
    bcast[0] = (float)mean;
    bcast[1] = (float)sqrt(var) + 1e-6f;
  }
  __syncthreads();
  float mean = bcast[0], stde = bcast[1];
  float thr2 = mean + 2.f * stde, thr3 = mean + 3.f * stde, thrf = mean - stde;
  int c2 = 0, c3 = 0, cf = 0;
  for (int l = threadIdx.x; l < LN; l += NTH) {
    float v = svm[l];
    c2 += (v > thr2); c3 += (v > thr3); cf += (v < thrf);
  }
  double ivals[3] = { (double)c2, (double)c3, (double)cf }; double outi[3];
  for (int q = 0; q < 3; q++) {
    red[threadIdx.x] = ivals[q]; __syncthreads();
    for (int st = NTH / 2; st > 0; st >>= 1) {
      if (threadIdx.x < st) red[threadIdx.x] += red[threadIdx.x + st];
      __syncthreads();
    }
    outi[q] = red[0]; __syncthreads();
  }
  if (threadIdx.x == 0) {
    float* stp = ws + OFF_SVM + b * 8;
    double n2 = LN / 2;
    double var2 = (out6[3] - out6[2] * out6[2] / n2) / (n2 - 1.0);
    if (var2 < 0) var2 = 0;
    float post_still = tanhf(1.f / ((float)sqrt(var2) + 1e-6f));
    float pre_mean = (float)(out6[4] / third);
    float post_mean = (float)(out6[5] / (LN - 2 * third));
    float pk = outf[1];
    float fp = fmaxf(pk - pre_mean, 0.f) + fmaxf(pk - post_mean, 0.f);
    fp = fp / (fabsf(pk) + 1e-6f);
    stp[0] = outf[0];                 // svm_max
    stp[1] = mean;                    // svm_mean
    stp[2] = (float)outi[0] / LN;     // impact_duration
    stp[3] = (float)outi[1] / LN;     // impact_ratio
    stp[4] = (float)outi[2] / LN;     // free_fall
    stp[5] = post_still;
    stp[6] = fp;
  }
}

// ---------------- K3: FFT (2 real channels packed per complex FFT) ----------------
__global__ __launch_bounds__(NTH) void k3_fft(const float* __restrict__ x, float* __restrict__ ws) {
  int blk = blockIdx.x;            // b*32 + cpair
  int b = blk >> 5, cp = blk & 31;
  const float* r0 = x + ((size_t)b * CN + 2 * cp) * LN;
  const float* r1 = r0 + LN;
  __shared__ float re[LN], im[LN];
  __shared__ float rA[NTH], rB[NTH], rC[NTH];
  for (int n = threadIdx.x; n < LN; n += NTH) {
    unsigned r = __brev((unsigned)n) >> 20;   // 12-bit reverse
    re[r] = r0[n];
    im[r] = r1[n];
  }
  __syncthreads();
  for (int s = 1; s <= 12; s++) {
    int half = 1 << (s - 1);
    for (int j = threadIdx.x; j < LN / 2; j += NTH) {
      int pos = j & (half - 1);
      int grp = j >> (s - 1);
      int i0 = (grp << s) + pos;
      int i1 = i0 + half;
      float ang = (float)pos / (float)half;   // units of pi
      float sv, cv;
      sincospif(ang, &sv, &cv);
      float wr = cv, wi = -sv;
      float ar = re[i1], ai = im[i1];
      float tr = wr * ar - wi * ai;
      float ti = wr * ai + wi * ar;
      float br = re[i0], bi = im[i0];
      re[i1] = br - tr; im[i1] = bi - ti;
      re[i0] = br + tr; im[i0] = bi + ti;
    }
    __syncthreads();
  }
  float tot = 0.f, cen = 0.f, hi = 0.f;
  for (int k = threadIdx.x; k <= LN / 2; k += NTH) {
    float p;
    if (k == 0 || k == LN / 2) {
      p = re[k] * re[k] + im[k] * im[k];
    } else {
      float zr = re[k], zi = im[k];
      float yr = re[LN - k], yi = im[LN - k];
      float a1 = zr + yr, a2 = zi - yi, a3 = zi + yi, a4 = zr - yr;
      p = 0.25f * (a1 * a1 + a2 * a2 + a3 * a3 + a4 * a4);
    }
    p *= (1.0f / LN);                       // ortho norm: |X|^2 / N
    tot += p;
    cen += p * ((float)k * (1.0f / (LN / 2)));
    if (k >= 820) hi += p;                  // k/2048 > 0.4
  }
  rA[threadIdx.x] = tot; rB[threadIdx.x] = cen; rC[threadIdx.x] = hi;
  __syncthreads();
  for (int st = NTH / 2; st > 0; st >>= 1) {
    if (threadIdx.x < st) {
      rA[threadIdx.x] += rA[threadIdx.x + st];
      rB[threadIdx.x] += rB[threadIdx.x + st];
      rC[threadIdx.x] += rC[threadIdx.x + st];
    }
    __syncthreads();
  }
  if (threadIdx.x == 0) {
    atomicAdd(&ws[OFF_SPEC + b * 3 + 0], rA[0]);
    atomicAdd(&ws[OFF_SPEC + b * 3 + 1], rB[0]);
    atomicAdd(&ws[OFF_SPEC + b * 3 + 2], rC[0]);
  }
}

// ---------------- K4: gate MLPs + mixture weights + effective conv kernels ----------------
__global__ __launch_bounds__(64) void k4_gate(
    const float* __restrict__ dw7, const float* __restrict__ dw15,
    const float* __restrict__ dw31, const float* __restrict__ dw63,
    const float* __restrict__ bn_g, const float* __restrict__ bn_b,
    const float* __restrict__ bn_m, const float* __restrict__ bn_v,
    const float* __restrict__ comp_w1, const float* __restrict__ comp_b1,
    const float* __restrict__ comp_w2, const float* __restrict__ comp_b2,
    const float* __restrict__ pn_g, const float* __restrict__ pn_b,
    const float* __restrict__ pn_m, const float* __restrict__ pn_v,
    const float* __restrict__ pe_w1, const float* __restrict__ pe_b1,
    const float* __restrict__ pe_w2, const float* __restrict__ pe_b2,
    const float* __restrict__ pg_w, const float* __restrict__ pg_b,
    const float* __restrict__ temperature,
    float* __restrict__ ws)
{
  int b = blockIdx.x, t = threadIdx.x;
  __shared__ float xm[64], h[64], pf[12], pe1v[32], pe2v[32], lgts[4], wts[4];
  xm[t] = ws[OFF_CHAN_SUM + b * 64 + t] * (1.0f / LN);
  float j  = ws[OFF_CHAN_JERK + b * 64 + t];
  float jr = ws[OFF_CHAN_JRATE + b * 64 + t];
  float z  = ws[OFF_CHAN_ZCR + b * 64 + t];
  for (int off = 32; off > 0; off >>= 1) {
    j  += __shfl_down(j, off);
    jr += __shfl_down(jr, off);
    z  += __shfl_down(z, off);
  }
  if (t == 0) {
    const float* stp = ws + OFF_SVM + b * 8;
    float tot = ws[OFF_SPEC + b * 3 + 0];
    float cenv = ws[OFF_SPEC + b * 3 + 1];
    float hiv = ws[OFF_SPEC + b * 3 + 2];
    pf[0] = stp[0]; pf[1] = stp[1];
    pf[2] = j * (1.f / 64);
    pf[3] = jr * (1.f / 64);
    pf[4] = (z * (1.f / 64)) * (1.f / LN);
    pf[5] = stp[2]; pf[6] = stp[3]; pf[7] = stp[5]; pf[8] = stp[4];
    pf[9] = cenv / (tot + 1e-6f);
    pf[10] = hiv / (tot + 1e-6f);
    pf[11] = stp[6];
  }
  __syncthreads();
  if (t < 12) pf[t] = (pf[t] - pn_m[t]) * rsqrtf(pn_v[t] + 1e-5f) * pn_g[t] + pn_b[t];
  __syncthreads();
  {
    float hv = comp_b1[t];
    for (int i = 0; i < 64; i++) hv = fmaf(xm[i], comp_w1[i * 64 + t], hv);
    h[t] = fmaxf(hv, 0.f);
  }
  if (t < 32) {
    float v = pe_b1[t];
    for (int i = 0; i < 12; i++) v = fmaf(pf[i], pe_w1[i * 32 + t], v);
    pe1v[t] = fmaxf(v, 0.f);
  }
  __syncthreads();
  if (t < 32) {
    float v = pe_b2[t];
    for (int i = 0; i < 32; i++) v = fmaf(pe1v[i], pe_w2[i * 32 + t], v);
    pe2v[t] = fmaxf(v, 0.f);
  }
  __syncthreads();
  if (t < 4) {
    float v = comp_b2[t];
    for (int i = 0; i < 64; i++) v = fmaf(h[i], comp_w2[i * 4 + t], v);
    float g = pg_b[t];
    for (int i = 0; i < 32; i++) g = fmaf(pe2v[i], pg_w[i * 4 + t], g);
    g = 1.f / (1.f + expf(-g));
    float temp = fmaxf(temperature[0], 0.1f);
    lgts[t] = v * g / temp;
  }
  __syncthreads();
  if (t < 4) {
    float m = fmaxf(fmaxf(lgts[0], lgts[1]), fmaxf(lgts[2], lgts[3]));
    float den = expf(lgts[0] - m) + expf(lgts[1] - m) + expf(lgts[2] - m) + expf(lgts[3] - m);
    wts[t] = expf(lgts[t] - m) / den;
  }
  __syncthreads();
  int c = t;
  float w0 = wts[0], w1 = wts[1], w2 = wts[2], w3 = wts[3];
  float s0 = bn_g[0 * 64 + c] * rsqrtf(bn_v[0 * 64 + c] + 1e-5f);
  float s1 = bn_g[1 * 64 + c] * rsqrtf(bn_v[1 * 64 + c] + 1e-5f);
  float s2 = bn_g[2 * 64 + c] * rsqrtf(bn_v[2 * 64 + c] + 1e-5f);
  float s3 = bn_g[3 * 64 + c] * rsqrtf(bn_v[3 * 64 + c] + 1e-5f);
  float o0 = bn_b[0 * 64 + c] - bn_m[0 * 64 + c] * s0;
  float o1 = bn_b[1 * 64 + c] - bn_m[1 * 64 + c] * s1;
  float o2 = bn_b[2 * 64 + c] - bn_m[2 * 64 + c] * s2;
  float o3 = bn_b[3 * 64 + c] - bn_m[3 * 64 + c] * s3;
  ws[OFF_EFF_B + b * 64 + c] = w0 * o0 + w1 * o1 + w2 * o2 + w3 * o3;
  float a0 = w0 * s0, a1 = w1 * s1, a2 = w2 * s2, a3 = w3 * s3;
  float* eff = ws + OFF_EFF_W + (size_t)(b * 64 + c) * 64;
  for (int tau = 0; tau < 64; tau++) {
    float v = 0.f;
    if (tau < 63) {
      v = a3 * dw63[c * 63 + tau];
      int i7 = tau - 28;  if (i7 >= 0 && i7 < 7)   v = fmaf(a0, dw7[c * 7 + i7], v);
      int i15 = tau - 24; if (i15 >= 0 && i15 < 15) v = fmaf(a1, dw15[c * 15 + i15], v);
      int i31 = tau - 16; if (i31 >= 0 && i31 < 31) v = fmaf(a2, dw31[c * 31 + i31], v);
    }
    eff[tau] = v;
  }
}

// ---------------- K5: effective 63-tap conv + GN stats; mixed -> d_out ----------------
__global__ __launch_bounds__(NTH) void k5_conv(const float* __restrict__ x,
                                               float* __restrict__ ws,
                                               float* __restrict__ mixed_out) {
  int bc = blockIdx.x;
  int b = bc >> 6;
  __shared__ float sx[LN + 80];
  __shared__ float wt[64];
  __shared__ float biasS;
  __shared__ double r1[NTH], r2[NTH];
  const float* row = x + (size_t)bc * LN;
  for (int i = threadIdx.x; i < LN + 80; i += NTH) {
    int g = i - 32;
    sx[i] = (g >= 0 && g < LN) ? row[g] : 0.f;
  }
  if (threadIdx.x < 64) wt[threadIdx.x] = ws[OFF_EFF_W + (size_t)bc * 64 + threadIdx.x];
  if (threadIdx.x == 0) biasS = ws[OFF_EFF_B + bc];
  __syncthreads();
  int l0 = threadIdx.x * 16;
  float xw[80];
#pragma unroll
  for (int i = 0; i < 80; i++) xw[i] = sx[l0 + i];
  float bias = biasS;
  float acc[16];
#pragma unroll
  for (int jj = 0; jj < 16; jj++) acc[jj] = bias;
#pragma unroll
  for (int tau = 0; tau < 63; tau++) {
    float w = wt[tau];
#pragma unroll
    for (int jj = 0; jj < 16; jj++) acc[jj] = fmaf(w, xw[jj + tau + 1], acc[jj]);
  }
  double ls = 0, ls2 = 0;
#pragma unroll
  for (int jj = 0; jj < 16; jj++) { float v = acc[jj]; ls += v; ls2 += (double)v * (double)v; }
  r1[threadIdx.x] = ls; r2[threadIdx.x] = ls2;
  __syncthreads();
  for (int st = NTH / 2; st > 0; st >>= 1) {
    if (threadIdx.x < st) { r1[threadIdx.x] += r1[threadIdx.x + st]; r2[threadIdx.x] += r2[threadIdx.x + st]; }
    __syncthreads();
  }
  if (threadIdx.x == 0) {
    double* gacc = (double*)(ws + OFF_GN);
    atomicAdd(&gacc[b * 2 + 0], r1[0]);
    atomicAdd(&gacc[b * 2 + 1], r2[0]);
  }
  float* dst = mixed_out + (size_t)bc * LN + l0;
#pragma unroll
  for (int q = 0; q < 4; q++) {
    float4 v; v.x = acc[4 * q]; v.y = acc[4 * q + 1]; v.z = acc[4 * q + 2]; v.w = acc[4 * q + 3];
    *(float4*)(dst + 4 * q) = v;
  }
}

// ---------------- K6: GN + GELU + proj + residual ----------------
__global__ __launch_bounds__(NTH) void k6_final(const float* __restrict__ x,
    const float* __restrict__ proj_w, const float* __restrict__ proj_b,
    const float* __restrict__ gn_g, const float* __restrict__ gn_b,
    const float* __restrict__ res_scale,
    const float* __restrict__ ws, float* out) {
  int blk = blockIdx.x;
  int b = blk >> 5;
  int l0 = (blk & 31) * 128;
  __shared__ float actS[64 * 128];
  __shared__ float Wt[64 * 64];
  const double* gacc = (const double*)(ws + OFF_GN);
  double s1 = gacc[b * 2 + 0], s2d = gacc[b * 2 + 1];
  const double NN = 64.0 * 4096.0;
  double mud = s1 / NN;
  float mu = (float)mud;
  float var = (float)(s2d / NN - mud * mud);
  float rstd = rsqrtf(var + 1e-5f);
  for (int i = threadIdx.x; i < 4096; i += NTH) {
    int o = i & 63, c = i >> 6;
    Wt[c * 64 + o] = proj_w[o * 64 + c];
  }
  const float* mx = out + (size_t)b * CN * LN;   // mixed lives in out
  for (int i = threadIdx.x; i < 8192; i += NTH) {
    int c = i >> 7, l = i & 127;
    float v = mx[(size_t)c * LN + l0 + l];
    float g = (v - mu) * rstd * gn_g[c] + gn_b[c];
    float a = 0.5f * g * (1.f + erff(g * 0.70710678118654752f));
    actS[c * 128 + l] = a;
  }
  __syncthreads();
  int lg = threadIdx.x & 31;         // l-subtile (4 l's)
  int og = (threadIdx.x >> 5) * 8;   // 8 o's
  float4 acc4[8];
#pragma unroll
  for (int q = 0; q < 8; q++) { acc4[q].x = 0.f; acc4[q].y = 0.f; acc4[q].z = 0.f; acc4[q].w = 0.f; }
  for (int c = 0; c < 64; c++) {
    float4 a = *(const float4*)&actS[c * 128 + lg * 4];
    float4 wlo = *(const float4*)&Wt[c * 64 + og];
    float4 whi = *(const float4*)&Wt[c * 64 + og + 4];
    float wv[8] = { wlo.x, wlo.y, wlo.z, wlo.w, whi.x, whi.y, whi.z, whi.w };
#pragma unroll
    for (int q = 0; q < 8; q++) {
      acc4[q].x = fmaf(wv[q], a.x, acc4[q].x);
      acc4[q].y = fmaf(wv[q], a.y, acc4[q].y);
      acc4[q].z = fmaf(wv[q], a.z, acc4[q].z);
      acc4[q].w = fmaf(wv[q], a.w, acc4[q].w);
    }
  }
  float rsv = res_scale[0];
  const float* xb = x + (size_t)b * CN * LN;
  float* ob = out + (size_t)b * CN * LN;
#pragma unroll
  for (int q = 0; q < 8; q++) {
    int o = og + q;
    float pb = proj_b[o];
    size_t base = (size_t)o * LN + l0 + lg * 4;
    float4 xv = *(const float4*)&xb[base];
    float4 r;
    r.x = xv.x + rsv * (acc4[q].x + pb);
    r.y = xv.y + rsv * (acc4[q].y + pb);
    r.z = xv.z + rsv * (acc4[q].z + pb);
    r.w = xv.w + rsv * (acc4[q].w + pb);
    *(float4*)&ob[base] = r;
  }
}

extern "C" void kernel_launch(void* const* d_in, const int* in_sizes, int n_in,
                              void* d_out, int out_size, void* d_ws, size_t ws_size,
                              hipStream_t stream) {
  const float* x        = (const float*)d_in[0];
  const float* dw7      = (const float*)d_in[1];
  const float* dw15     = (const float*)d_in[2];
  const float* dw31     = (const float*)d_in[3];
  const float* dw63     = (const float*)d_in[4];
  const float* bn_g     = (const float*)d_in[5];
  const float* bn_b     = (const float*)d_in[6];
  const float* bn_m     = (const float*)d_in[7];
  const float* bn_v     = (const float*)d_in[8];
  const float* comp_w1  = (const float*)d_in[9];
  const float* comp_b1  = (const float*)d_in[10];
  const float* comp_w2  = (const float*)d_in[11];
  const float* comp_b2  = (const float*)d_in[12];
  const float* pn_g     = (const float*)d_in[13];
  const float* pn_b     = (const float*)d_in[14];
  const float* pn_m     = (const float*)d_in[15];
  const float* pn_v     = (const float*)d_in[16];
  const float* pe_w1    = (const float*)d_in[17];
  const float* pe_b1    = (const float*)d_in[18];
  const float* pe_w2    = (const float*)d_in[19];
  const float* pe_b2    = (const float*)d_in[20];
  const float* pg_w     = (const float*)d_in[21];
  const float* pg_b     = (const float*)d_in[22];
  const float* temperature = (const float*)d_in[23];
  const float* gn_g     = (const float*)d_in[24];
  const float* gn_b     = (const float*)d_in[25];
  const float* proj_w   = (const float*)d_in[26];
  const float* proj_b   = (const float*)d_in[27];
  const float* res_scale= (const float*)d_in[28];
  float* ws = (float*)d_ws;
  float* out = (float*)d_out;

  hipLaunchKernelGGL(k0_zero, dim3(1), dim3(256), 0, stream, ws);
  hipLaunchKernelGGL(k1_chan, dim3(BQ * CN), dim3(NTH), 0, stream, x, ws);
  hipLaunchKernelGGL(k2_svm, dim3(BQ), dim3(NTH), 0, stream, x, ws);
  hipLaunchKernelGGL(k3_fft, dim3(BQ * 32), dim3(NTH), 0, stream, x, ws);
  hipLaunchKernelGGL(k4_gate, dim3(BQ), dim3(64), 0, stream,
                     dw7, dw15, dw31, dw63, bn_g, bn_b, bn_m, bn_v,
                     comp_w1, comp_b1, comp_w2, comp_b2,
                     pn_g, pn_b, pn_m, pn_v, pe_w1, pe_b1, pe_w2, pe_b2,
                     pg_w, pg_b, temperature, ws);
  hipLaunchKernelGGL(k5_conv, dim3(BQ * CN), dim3(NTH), 0, stream, x, ws, out);
  hipLaunchKernelGGL(k6_final, dim3(BQ * 32), dim3(NTH), 0, stream,
                     x, proj_w, proj_b, gn_g, gn_b, res_scale, ws, out);
}

// Round 2
// 289.681 us; speedup vs baseline: 1.1495x; 1.1495x over previous
//
#include <hip/hip_runtime.h>
#include <math.h>

#define LN 4096
#define CN 64
#define BQ 32
#define NTH 256

// ws offsets (floats)
#define OFF_CHAN_SUM   0        // 2048
#define OFF_CHAN_JERK  2048     // 2048
#define OFF_CHAN_JRATE 4096     // 2048
#define OFF_CHAN_ZCR   6144     // 2048
#define OFF_SVMST      8192     // 32*16 per-b stat accumulators
#define OFF_SPEC       8704     // 32*3
#define OFF_EFF_B      8800     // 2048
#define OFF_GN         10848    // 64 doubles = 128 floats (byte off 43392 %8==0)
#define OFF_EFF_W      10976    // 2048*64
#define OFF_SVMBUF     142048   // 32*4096
// total 273120 floats = 1.09 MB

// ---------------- K0: zero atomic accumulators ----------------
__global__ void k0_zero(float* __restrict__ ws) {
  int t = threadIdx.x;
  if (t < 512) ws[OFF_SVMST + t] = 0.f;
  if (t < 96)  ws[OFF_SPEC + t] = 0.f;
  if (t < 128) ws[OFF_GN + t] = 0.f;
}

// ---------------- K1: per-(b,c) scans, register chunks + shuffle reduce ----------------
__global__ __launch_bounds__(NTH) void k1_chan(const float* __restrict__ x, float* __restrict__ ws) {
  int bc = blockIdx.x;
  const float* row = x + (size_t)bc * LN;
  int t = threadIdx.x;
  int l0 = t * 16;
  float rd[18];
  const float4* r4 = (const float4*)(row + l0);
#pragma unroll
  for (int q = 0; q < 4; q++) {
    float4 v = r4[q];
    rd[4*q] = v.x; rd[4*q+1] = v.y; rd[4*q+2] = v.z; rd[4*q+3] = v.w;
  }
  if (t < 255) { rd[16] = row[l0 + 16]; rd[17] = row[l0 + 17]; }
  else { rd[16] = 0.f; rd[17] = 0.f; }
  float lsum = 0.f, jm = 0.f, jrm = 0.f; int zc = 0;
#pragma unroll
  for (int i = 0; i < 16; i++) {
    float a = rd[i], b2 = rd[i+1];
    lsum += a;
    int l = l0 + i;
    if (l < LN - 1) {
      jm = fmaxf(jm, fabsf(b2 - a));
      zc += (a * b2 < 0.f);
      if (l < LN - 2) jrm = fmaxf(jrm, fabsf(rd[i+2] - 2.f*b2 + a));
    }
  }
  for (int off = 32; off > 0; off >>= 1) {
    lsum += __shfl_down(lsum, off);
    jm = fmaxf(jm, __shfl_down(jm, off));
    jrm = fmaxf(jrm, __shfl_down(jrm, off));
    zc += __shfl_down(zc, off);
  }
  __shared__ float s1[4], s2_[4], s3[4]; __shared__ int s4[4];
  int w = t >> 6;
  if ((t & 63) == 0) { s1[w] = lsum; s2_[w] = jm; s3[w] = jrm; s4[w] = zc; }
  __syncthreads();
  if (t == 0) {
    float S = 0, J = 0, JR = 0; int Z = 0;
    for (int i = 0; i < 4; i++) { S += s1[i]; J = fmaxf(J, s2_[i]); JR = fmaxf(JR, s3[i]); Z += s4[i]; }
    ws[OFF_CHAN_SUM + bc]   = S;
    ws[OFF_CHAN_JERK + bc]  = J * 50.f;
    ws[OFF_CHAN_JRATE + bc] = JR * 2500.f;
    ws[OFF_CHAN_ZCR + bc]   = (float)Z;
  }
}

// ---------------- KA: svm + partial stats (512 blocks) ----------------
__global__ __launch_bounds__(NTH) void kA_svm(const float* __restrict__ x, float* __restrict__ ws) {
  int blk = blockIdx.x;            // b*16 + lt
  int b = blk >> 4, lt = blk & 15;
  int t = threadIdx.x;
  int l = lt * 256 + t;
  const float* xb = x + (size_t)b * CN * LN + l;
  float acc = 0.f;
#pragma unroll
  for (int c = 0; c < CN; c++) { float v = xb[(size_t)c * LN]; acc = fmaf(v, v, acc); }
  float svm = sqrtf(acc);
  ws[OFF_SVMBUF + (size_t)b * LN + l] = svm;
  const int third = LN / 3;        // 1365
  float vS = svm, vS2 = svm * svm;
  float vS2H  = (l >= LN/2) ? svm : 0.f;
  float vS2H2 = (l >= LN/2) ? svm * svm : 0.f;
  float vPRE  = (l < third) ? svm : 0.f;
  float vPOST = (l >= 2*third) ? svm : 0.f;
  float vMX = svm;
  float vMID = (l >= third && l < 2*third) ? svm : 0.f;
  for (int off = 32; off > 0; off >>= 1) {
    vS += __shfl_down(vS, off); vS2 += __shfl_down(vS2, off);
    vS2H += __shfl_down(vS2H, off); vS2H2 += __shfl_down(vS2H2, off);
    vPRE += __shfl_down(vPRE, off); vPOST += __shfl_down(vPOST, off);
    vMX = fmaxf(vMX, __shfl_down(vMX, off));
    vMID = fmaxf(vMID, __shfl_down(vMID, off));
  }
  __shared__ float red[8][4];
  int w = t >> 6;
  if ((t & 63) == 0) {
    red[0][w] = vS; red[1][w] = vS2; red[2][w] = vMX; red[3][w] = vS2H;
    red[4][w] = vS2H2; red[5][w] = vPRE; red[6][w] = vMID; red[7][w] = vPOST;
  }
  __syncthreads();
  if (t == 0) {
    float S = red[0][0]+red[0][1]+red[0][2]+red[0][3];
    float S2 = red[1][0]+red[1][1]+red[1][2]+red[1][3];
    float MX = fmaxf(fmaxf(red[2][0],red[2][1]),fmaxf(red[2][2],red[2][3]));
    float S2H = red[3][0]+red[3][1]+red[3][2]+red[3][3];
    float S2H2 = red[4][0]+red[4][1]+red[4][2]+red[4][3];
    float PRE = red[5][0]+red[5][1]+red[5][2]+red[5][3];
    float MID = fmaxf(fmaxf(red[6][0],red[6][1]),fmaxf(red[6][2],red[6][3]));
    float POST = red[7][0]+red[7][1]+red[7][2]+red[7][3];
    float* st = ws + OFF_SVMST + b * 16;
    atomicAdd(&st[0], S); atomicAdd(&st[1], S2);
    atomicMax((int*)&st[2], __float_as_int(MX));
    atomicAdd(&st[3], S2H); atomicAdd(&st[4], S2H2);
    atomicAdd(&st[5], PRE);
    atomicMax((int*)&st[6], __float_as_int(MID));
    atomicAdd(&st[7], POST);
  }
}

// ---------------- K3: radix-4 FFT, float2 LDS with skew pad ----------------
#define FP(i) ((i) + ((i) >> 4))
__global__ __launch_bounds__(NTH) void k3_fft(const float* __restrict__ x, float* __restrict__ ws) {
  int blk = blockIdx.x;            // b*32 + cpair
  int b = blk >> 5, cp = blk & 31;
  const float* r0 = x + ((size_t)b * CN + 2 * cp) * LN;
  const float* r1 = r0 + LN;
  __shared__ float2 z[FP(4096)];   // 4352 float2 = 34816 B
  __shared__ float red[3][4];
  int t = threadIdx.x;
  // load with base-4 digit-reversal
#pragma unroll
  for (int k = 0; k < 4; k++) {
    int n4 = (k * 256 + t) * 4;
    float4 a = *(const float4*)(r0 + n4);
    float4 c = *(const float4*)(r1 + n4);
    float ar[4] = {a.x, a.y, a.z, a.w}, cr[4] = {c.x, c.y, c.z, c.w};
#pragma unroll
    for (int q = 0; q < 4; q++) {
      unsigned n = (unsigned)(n4 + q);
      unsigned br = __brev(n) >> 20;
      unsigned dr = ((br & 0x555u) << 1) | ((br & 0xAAAu) >> 1);
      z[FP(dr)] = make_float2(ar[q], cr[q]);
    }
  }
  __syncthreads();
  // stage 0 (half=1): twiddles are all 1
#pragma unroll
  for (int u = 0; u < 4; u++) {
    int j = u * 256 + t;
    int i0 = 4 * j;
    float2 x0 = z[FP(i0)], x1 = z[FP(i0+1)], x2 = z[FP(i0+2)], x3 = z[FP(i0+3)];
    float ar = x0.x + x2.x, ai = x0.y + x2.y;
    float br_ = x0.x - x2.x, bi = x0.y - x2.y;
    float cr = x1.x + x3.x, ci = x1.y + x3.y;
    float dr_ = x1.x - x3.x, di = x1.y - x3.y;
    z[FP(i0)]   = make_float2(ar + cr, ai + ci);
    z[FP(i0+1)] = make_float2(br_ + di, bi - dr_);
    z[FP(i0+2)] = make_float2(ar - cr, ai - ci);
    z[FP(i0+3)] = make_float2(br_ - di, bi + dr_);
  }
  __syncthreads();
  // stages 1..5
#pragma unroll
  for (int s = 1; s < 6; s++) {
    int half = 1 << (2 * s);
    float angscale = 1.0f / (float)(2 * half);
#pragma unroll
    for (int u = 0; u < 4; u++) {
      int j = u * 256 + t;
      int pos = j & (half - 1);
      int i0 = ((j >> (2 * s)) << (2 * s + 2)) + pos;
      float2 x0 = z[FP(i0)];
      float2 x1 = z[FP(i0 + half)];
      float2 x2 = z[FP(i0 + 2 * half)];
      float2 x3 = z[FP(i0 + 3 * half)];
      float sv, cv;
      sincospif((float)pos * angscale, &sv, &cv);
      float w1r = cv, w1i = -sv;
      float w2r = w1r*w1r - w1i*w1i, w2i = 2.f*w1r*w1i;
      float w3r = w2r*w1r - w2i*w1i, w3i = w2r*w1i + w2i*w1r;
      float t1r = x1.x*w1r - x1.y*w1i, t1i = x1.x*w1i + x1.y*w1r;
      float t2r = x2.x*w2r - x2.y*w2i, t2i = x2.x*w2i + x2.y*w2r;
      float t3r = x3.x*w3r - x3.y*w3i, t3i = x3.x*w3i + x3.y*w3r;
      float ar = x0.x + t2r, ai = x0.y + t2i;
      float br_ = x0.x - t2r, bi = x0.y - t2i;
      float cr = t1r + t3r, ci = t1i + t3i;
      float dr_ = t1r - t3r, di = t1i - t3i;
      z[FP(i0)]            = make_float2(ar + cr, ai + ci);
      z[FP(i0 + half)]     = make_float2(br_ + di, bi - dr_);
      z[FP(i0 + 2*half)]   = make_float2(ar - cr, ai - ci);
      z[FP(i0 + 3*half)]   = make_float2(br_ - di, bi + dr_);
    }
    __syncthreads();
  }
  // power + spectral partial sums (conjugate-symmetry unpack of 2 packed real channels)
  float tot = 0.f, cen = 0.f, hi = 0.f;
  for (int k = t; k <= LN / 2; k += NTH) {
    float p;
    if (k == 0 || k == LN / 2) {
      float2 v = z[FP(k)];
      p = v.x * v.x + v.y * v.y;
    } else {
      float2 zk = z[FP(k)], zn = z[FP(LN - k)];
      float a1 = zk.x + zn.x, a2 = zk.y - zn.y, a3 = zk.y + zn.y, a4 = zk.x - zn.x;
      p = 0.25f * (a1*a1 + a2*a2 + a3*a3 + a4*a4);
    }
    p *= (1.0f / LN);
    tot += p;
    cen += p * ((float)k * (1.0f / (LN / 2)));
    if (k >= 820) hi += p;
  }
  for (int off = 32; off > 0; off >>= 1) {
    tot += __shfl_down(tot, off);
    cen += __shfl_down(cen, off);
    hi  += __shfl_down(hi, off);
  }
  int w = t >> 6;
  if ((t & 63) == 0) { red[0][w] = tot; red[1][w] = cen; red[2][w] = hi; }
  __syncthreads();
  if (t == 0) {
    atomicAdd(&ws[OFF_SPEC + b*3 + 0], red[0][0]+red[0][1]+red[0][2]+red[0][3]);
    atomicAdd(&ws[OFF_SPEC + b*3 + 1], red[1][0]+red[1][1]+red[1][2]+red[1][3]);
    atomicAdd(&ws[OFF_SPEC + b*3 + 2], red[2][0]+red[2][1]+red[2][2]+red[2][3]);
  }
}

// ---------------- K4: threshold counts + gate MLPs + effective conv kernels ----------------
__global__ __launch_bounds__(NTH) void k4_gate(
    const float* __restrict__ dw7, const float* __restrict__ dw15,
    const float* __restrict__ dw31, const float* __restrict__ dw63,
    const float* __restrict__ bn_g, const float* __restrict__ bn_b,
    const float* __restrict__ bn_m, const float* __restrict__ bn_v,
    const float* __restrict__ comp_w1, const float* __restrict__ comp_b1,
    const float* __restrict__ comp_w2, const float* __restrict__ comp_b2,
    const float* __restrict__ pn_g, const float* __restrict__ pn_b,
    const float* __restrict__ pn_m, const float* __restrict__ pn_v,
    const float* __restrict__ pe_w1, const float* __restrict__ pe_b1,
    const float* __restrict__ pe_w2, const float* __restrict__ pe_b2,
    const float* __restrict__ pg_w, const float* __restrict__ pg_b,
    const float* __restrict__ temperature,
    float* __restrict__ ws)
{
  int b = blockIdx.x, t = threadIdx.x;
  __shared__ float xm[64], h[64], pf[12], pe1v[32], pe2v[32], lgts[4], wts[4];
  __shared__ int ri[3][4], cnts[3];
  const float* st = ws + OFF_SVMST + b * 16;
  float S = st[0], S2 = st[1];
  float mean = S * (1.f / LN);
  float var = (S2 - S * S * (1.f / LN)) * (1.f / (LN - 1));
  var = fmaxf(var, 0.f);
  float stde = sqrtf(var) + 1e-6f;
  float thr2 = mean + 2.f * stde, thr3 = mean + 3.f * stde, thrf = mean - stde;
  const float* svm = ws + OFF_SVMBUF + (size_t)b * LN;
  int c2 = 0, c3 = 0, cf = 0;
  for (int l = t; l < LN; l += NTH) {
    float v = svm[l];
    c2 += (v > thr2); c3 += (v > thr3); cf += (v < thrf);
  }
  for (int off = 32; off > 0; off >>= 1) {
    c2 += __shfl_down(c2, off); c3 += __shfl_down(c3, off); cf += __shfl_down(cf, off);
  }
  int w = t >> 6;
  if ((t & 63) == 0) { ri[0][w] = c2; ri[1][w] = c3; ri[2][w] = cf; }
  float j = 0.f, jr = 0.f, zz = 0.f;
  if (t < 64) {
    xm[t] = ws[OFF_CHAN_SUM + b * 64 + t] * (1.0f / LN);
    j  = ws[OFF_CHAN_JERK + b * 64 + t];
    jr = ws[OFF_CHAN_JRATE + b * 64 + t];
    zz = ws[OFF_CHAN_ZCR + b * 64 + t];
    for (int off = 32; off > 0; off >>= 1) {
      j += __shfl_down(j, off); jr += __shfl_down(jr, off); zz += __shfl_down(zz, off);
    }
  }
  __syncthreads();
  if (t == 0) {
    cnts[0] = ri[0][0]+ri[0][1]+ri[0][2]+ri[0][3];
    cnts[1] = ri[1][0]+ri[1][1]+ri[1][2]+ri[1][3];
    cnts[2] = ri[2][0]+ri[2][1]+ri[2][2]+ri[2][3];
    float tot = ws[OFF_SPEC + b*3 + 0];
    float cenv = ws[OFF_SPEC + b*3 + 1];
    float hiv = ws[OFF_SPEC + b*3 + 2];
    const int third = LN / 3;
    float S2H = st[3], S2H2 = st[4];
    float n2 = (float)(LN / 2);
    float var2 = (S2H2 - S2H * S2H / n2) / (n2 - 1.f);
    var2 = fmaxf(var2, 0.f);
    float post_still = tanhf(1.f / (sqrtf(var2) + 1e-6f));
    float pre_mean = st[5] / (float)third;
    float post_mean = st[7] / (float)(LN - 2 * third);
    float pk = st[6];
    float fp = fmaxf(pk - pre_mean, 0.f) + fmaxf(pk - post_mean, 0.f);
    fp = fp / (fabsf(pk) + 1e-6f);
    pf[0] = st[2];                     // svm_max
    pf[1] = mean;
    pf[2] = j * (1.f / 64);
    pf[3] = jr * (1.f / 64);
    pf[4] = (zz * (1.f / 64)) * (1.f / LN);
    pf[5] = (float)cnts[0] / LN;
    pf[6] = (float)cnts[1] / LN;
    pf[7] = post_still;
    pf[8] = (float)cnts[2] / LN;
    pf[9] = cenv / (tot + 1e-6f);
    pf[10] = hiv / (tot + 1e-6f);
    pf[11] = fp;
  }
  __syncthreads();
  if (t < 12) pf[t] = (pf[t] - pn_m[t]) * rsqrtf(pn_v[t] + 1e-5f) * pn_g[t] + pn_b[t];
  __syncthreads();
  if (t < 64) {
    float hv = comp_b1[t];
    for (int i = 0; i < 64; i++) hv = fmaf(xm[i], comp_w1[i * 64 + t], hv);
    h[t] = fmaxf(hv, 0.f);
  }
  if (t < 32) {
    float v = pe_b1[t];
    for (int i = 0; i < 12; i++) v = fmaf(pf[i], pe_w1[i * 32 + t], v);
    pe1v[t] = fmaxf(v, 0.f);
  }
  __syncthreads();
  if (t < 32) {
    float v = pe_b2[t];
    for (int i = 0; i < 32; i++) v = fmaf(pe1v[i], pe_w2[i * 32 + t], v);
    pe2v[t] = fmaxf(v, 0.f);
  }
  __syncthreads();
  if (t < 4) {
    float v = comp_b2[t];
    for (int i = 0; i < 64; i++) v = fmaf(h[i], comp_w2[i * 4 + t], v);
    float g = pg_b[t];
    for (int i = 0; i < 32; i++) g = fmaf(pe2v[i], pg_w[i * 4 + t], g);
    g = 1.f / (1.f + expf(-g));
    float temp = fmaxf(temperature[0], 0.1f);
    lgts[t] = v * g / temp;
  }
  __syncthreads();
  if (t < 4) {
    float m = fmaxf(fmaxf(lgts[0], lgts[1]), fmaxf(lgts[2], lgts[3]));
    float den = expf(lgts[0]-m) + expf(lgts[1]-m) + expf(lgts[2]-m) + expf(lgts[3]-m);
    wts[t] = expf(lgts[t] - m) / den;
  }
  __syncthreads();
  if (t < 64) {
    int c = t;
    float w0 = wts[0], w1 = wts[1], w2 = wts[2], w3 = wts[3];
    float sc0 = bn_g[0*64+c] * rsqrtf(bn_v[0*64+c] + 1e-5f);
    float sc1 = bn_g[1*64+c] * rsqrtf(bn_v[1*64+c] + 1e-5f);
    float sc2 = bn_g[2*64+c] * rsqrtf(bn_v[2*64+c] + 1e-5f);
    float sc3 = bn_g[3*64+c] * rsqrtf(bn_v[3*64+c] + 1e-5f);
    float o0 = bn_b[0*64+c] - bn_m[0*64+c] * sc0;
    float o1 = bn_b[1*64+c] - bn_m[1*64+c] * sc1;
    float o2 = bn_b[2*64+c] - bn_m[2*64+c] * sc2;
    float o3 = bn_b[3*64+c] - bn_m[3*64+c] * sc3;
    ws[OFF_EFF_B + b * 64 + c] = w0*o0 + w1*o1 + w2*o2 + w3*o3;
    float a0 = w0*sc0, a1 = w1*sc1, a2 = w2*sc2, a3 = w3*sc3;
    float* eff = ws + OFF_EFF_W + (size_t)(b * 64 + c) * 64;
    for (int tau = 0; tau < 64; tau++) {
      float v = 0.f;
      if (tau < 63) {
        v = a3 * dw63[c * 63 + tau];
        int i7 = tau - 28;  if (i7 >= 0 && i7 < 7)   v = fmaf(a0, dw7[c * 7 + i7], v);
        int i15 = tau - 24; if (i15 >= 0 && i15 < 15) v = fmaf(a1, dw15[c * 15 + i15], v);
        int i31 = tau - 16; if (i31 >= 0 && i31 < 31) v = fmaf(a2, dw31[c * 31 + i31], v);
      }
      eff[tau] = v;
    }
  }
}

// ---------------- K5: effective 63-tap conv + GN stats; mixed -> d_out ----------------
__global__ __launch_bounds__(NTH) void k5_conv(const float* __restrict__ x,
                                               float* __restrict__ ws,
                                               float* __restrict__ mixed_out) {
  int bc = blockIdx.x;
  int b = bc >> 6;
  __shared__ float sx[LN + 80];
  __shared__ float wt[64];
  __shared__ float biasS;
  __shared__ double rda[2][4];
  const float* row = x + (size_t)bc * LN;
  for (int i = threadIdx.x; i < LN + 80; i += NTH) {
    int g = i - 32;
    sx[i] = (g >= 0 && g < LN) ? row[g] : 0.f;
  }
  if (threadIdx.x < 64) wt[threadIdx.x] = ws[OFF_EFF_W + (size_t)bc * 64 + threadIdx.x];
  if (threadIdx.x == 0) biasS = ws[OFF_EFF_B + bc];
  __syncthreads();
  int l0 = threadIdx.x * 16;
  float xw[80];
#pragma unroll
  for (int i = 0; i < 80; i++) xw[i] = sx[l0 + i];
  float bias = biasS;
  float acc[16];
#pragma unroll
  for (int jj = 0; jj < 16; jj++) acc[jj] = bias;
#pragma unroll
  for (int tau = 0; tau < 63; tau++) {
    float w = wt[tau];
#pragma unroll
    for (int jj = 0; jj < 16; jj++) acc[jj] = fmaf(w, xw[jj + tau + 1], acc[jj]);
  }
  double ls = 0, ls2 = 0;
#pragma unroll
  for (int jj = 0; jj < 16; jj++) { float v = acc[jj]; ls += v; ls2 += (double)v * (double)v; }
  for (int off = 32; off > 0; off >>= 1) {
    ls += __shfl_down(ls, off);
    ls2 += __shfl_down(ls2, off);
  }
  int w = threadIdx.x >> 6;
  if ((threadIdx.x & 63) == 0) { rda[0][w] = ls; rda[1][w] = ls2; }
  __syncthreads();
  if (threadIdx.x == 0) {
    double* gacc = (double*)(ws + OFF_GN);
    atomicAdd(&gacc[b * 2 + 0], rda[0][0]+rda[0][1]+rda[0][2]+rda[0][3]);
    atomicAdd(&gacc[b * 2 + 1], rda[1][0]+rda[1][1]+rda[1][2]+rda[1][3]);
  }
  float* dst = mixed_out + (size_t)bc * LN + l0;
#pragma unroll
  for (int q = 0; q < 4; q++) {
    float4 v; v.x = acc[4*q]; v.y = acc[4*q+1]; v.z = acc[4*q+2]; v.w = acc[4*q+3];
    *(float4*)(dst + 4 * q) = v;
  }
}

// ---------------- K6: GN + GELU + proj + residual ----------------
__global__ __launch_bounds__(NTH) void k6_final(const float* __restrict__ x,
    const float* __restrict__ proj_w, const float* __restrict__ proj_b,
    const float* __restrict__ gn_g, const float* __restrict__ gn_b,
    const float* __restrict__ res_scale,
    const float* __restrict__ ws, float* out) {
  int blk = blockIdx.x;
  int b = blk >> 5;
  int l0 = (blk & 31) * 128;
  __shared__ float actS[64 * 128];
  __shared__ float Wt[64 * 64];
  const double* gacc = (const double*)(ws + OFF_GN);
  double s1 = gacc[b * 2 + 0], s2d = gacc[b * 2 + 1];
  const double NN = 64.0 * 4096.0;
  double mud = s1 / NN;
  float mu = (float)mud;
  float var = (float)(s2d / NN - mud * mud);
  float rstd = rsqrtf(var + 1e-5f);
  for (int i = threadIdx.x; i < 4096; i += NTH) {
    int o = i & 63, c = i >> 6;
    Wt[c * 64 + o] = proj_w[o * 64 + c];
  }
  const float* mx = out + (size_t)b * CN * LN;
  for (int i = threadIdx.x; i < 8192; i += NTH) {
    int c = i >> 7, l = i & 127;
    float v = mx[(size_t)c * LN + l0 + l];
    float g = (v - mu) * rstd * gn_g[c] + gn_b[c];
    float a = 0.5f * g * (1.f + erff(g * 0.70710678118654752f));
    actS[c * 128 + l] = a;
  }
  __syncthreads();
  int lg = threadIdx.x & 31;
  int og = (threadIdx.x >> 5) * 8;
  float4 acc4[8];
#pragma unroll
  for (int q = 0; q < 8; q++) { acc4[q].x = 0.f; acc4[q].y = 0.f; acc4[q].z = 0.f; acc4[q].w = 0.f; }
  for (int c = 0; c < 64; c++) {
    float4 a = *(const float4*)&actS[c * 128 + lg * 4];
    float4 wlo = *(const float4*)&Wt[c * 64 + og];
    float4 whi = *(const float4*)&Wt[c * 64 + og + 4];
    float wv[8] = { wlo.x, wlo.y, wlo.z, wlo.w, whi.x, whi.y, whi.z, whi.w };
#pragma unroll
    for (int q = 0; q < 8; q++) {
      acc4[q].x = fmaf(wv[q], a.x, acc4[q].x);
      acc4[q].y = fmaf(wv[q], a.y, acc4[q].y);
      acc4[q].z = fmaf(wv[q], a.z, acc4[q].z);
      acc4[q].w = fmaf(wv[q], a.w, acc4[q].w);
    }
  }
  float rsv = res_scale[0];
  const float* xb = x + (size_t)b * CN * LN;
  float* ob = out + (size_t)b * CN * LN;
#pragma unroll
  for (int q = 0; q < 8; q++) {
    int o = og + q;
    float pb = proj_b[o];
    size_t base = (size_t)o * LN + l0 + lg * 4;
    float4 xv = *(const float4*)&xb[base];
    float4 r;
    r.x = xv.x + rsv * (acc4[q].x + pb);
    r.y = xv.y + rsv * (acc4[q].y + pb);
    r.z = xv.z + rsv * (acc4[q].z + pb);
    r.w = xv.w + rsv * (acc4[q].w + pb);
    *(float4*)&ob[base] = r;
  }
}

extern "C" void kernel_launch(void* const* d_in, const int* in_sizes, int n_in,
                              void* d_out, int out_size, void* d_ws, size_t ws_size,
                              hipStream_t stream) {
  const float* x        = (const float*)d_in[0];
  const float* dw7      = (const float*)d_in[1];
  const float* dw15     = (const float*)d_in[2];
  const float* dw31     = (const float*)d_in[3];
  const float* dw63     = (const float*)d_in[4];
  const float* bn_g     = (const float*)d_in[5];
  const float* bn_b     = (const float*)d_in[6];
  const float* bn_m     = (const float*)d_in[7];
  const float* bn_v     = (const float*)d_in[8];
  const float* comp_w1  = (const float*)d_in[9];
  const float* comp_b1  = (const float*)d_in[10];
  const float* comp_w2  = (const float*)d_in[11];
  const float* comp_b2  = (const float*)d_in[12];
  const float* pn_g     = (const float*)d_in[13];
  const float* pn_b     = (const float*)d_in[14];
  const float* pn_m     = (const float*)d_in[15];
  const float* pn_v     = (const float*)d_in[16];
  const float* pe_w1    = (const float*)d_in[17];
  const float* pe_b1    = (const float*)d_in[18];
  const float* pe_w2    = (const float*)d_in[19];
  const float* pe_b2    = (const float*)d_in[20];
  const float* pg_w     = (const float*)d_in[21];
  const float* pg_b     = (const float*)d_in[22];
  const float* temperature = (const float*)d_in[23];
  const float* gn_g     = (const float*)d_in[24];
  const float* gn_b     = (const float*)d_in[25];
  const float* proj_w   = (const float*)d_in[26];
  const float* proj_b   = (const float*)d_in[27];
  const float* res_scale= (const float*)d_in[28];
  float* ws = (float*)d_ws;
  float* out = (float*)d_out;

  hipLaunchKernelGGL(k0_zero, dim3(1), dim3(512), 0, stream, ws);
  hipLaunchKernelGGL(k1_chan, dim3(BQ * CN), dim3(NTH), 0, stream, x, ws);
  hipLaunchKernelGGL(kA_svm, dim3(BQ * 16), dim3(NTH), 0, stream, x, ws);
  hipLaunchKernelGGL(k3_fft, dim3(BQ * 32), dim3(NTH), 0, stream, x, ws);
  hipLaunchKernelGGL(k4_gate, dim3(BQ), dim3(NTH), 0, stream,
                     dw7, dw15, dw31, dw63, bn_g, bn_b, bn_m, bn_v,
                     comp_w1, comp_b1, comp_w2, comp_b2,
                     pn_g, pn_b, pn_m, pn_v, pe_w1, pe_b1, pe_w2, pe_b2,
                     pg_w, pg_b, temperature, ws);
  hipLaunchKernelGGL(k5_conv, dim3(BQ * CN), dim3(NTH), 0, stream, x, ws, out);
  hipLaunchKernelGGL(k6_final, dim3(BQ * 32), dim3(NTH), 0, stream,
                     x, proj_w, proj_b, gn_g, gn_b, res_scale, ws, out);
}